// Round 8
// baseline (116.549 us; speedup 1.0000x reference)
//
#include <hip/hip_runtime.h>
#include <math.h>

constexpr int BATCH = 256;

// ---------------------------------------------------------------------------
// basis_eval: 8 cubic B-spline values + silu. out[0..7]=basis, out[8]=silu.
// ---------------------------------------------------------------------------
__device__ __forceinline__ void basis_eval(
    float x, const float* __restrict__ grid, int ii, float out[9])
{
    float g[6];
#pragma unroll
    for (int k = 0; k < 6; ++k) g[k] = grid[(size_t)ii * 6 + k];
    float h = (g[5] - g[0]) * 0.2f;

    float t[12];
    t[0] = g[0] - 3.f * h; t[1] = g[0] - 2.f * h; t[2] = g[0] - h;
#pragma unroll
    for (int k = 0; k < 6; ++k) t[3 + k] = g[k];
    t[9] = g[5] + h; t[10] = g[5] + 2.f * h; t[11] = g[5] + 3.f * h;

    float Bv[11];
#pragma unroll
    for (int j = 0; j < 11; ++j)
        Bv[j] = (x >= t[j] && x < t[j + 1]) ? 1.0f : 0.0f;

#pragma unroll
    for (int d = 1; d <= 3; ++d) {
#pragma unroll
        for (int j = 0; j + d < 11; ++j) {
            float left  = __fdividef(x - t[j],         t[j + d] - t[j]);
            float right = __fdividef(t[j + d + 1] - x, t[j + d + 1] - t[j + 1]);
            Bv[j] = left * Bv[j] + right * Bv[j + 1];
        }
    }

#pragma unroll
    for (int k = 0; k < 8; ++k) out[k] = Bv[k];
    out[8] = __fdividef(x, 1.0f + __expf(-x));
}

// ---------------------------------------------------------------------------
// merge: wcA[s*12+k] = ssp[s]*coef[s*8+k] (k<8), wcA[s*12+8] = sb[s]
// ---------------------------------------------------------------------------
__device__ __forceinline__ void merge_body(
    const float* __restrict__ coef, const float* __restrict__ ssp,
    const float* __restrict__ sb, float* __restrict__ wcA, int s)
{
    float sspv = ssp[s], sbv = sb[s];
    const float4* c = (const float4*)(coef + (size_t)s * 8);
    float4 c0 = c[0], c1 = c[1];
    float4* w = (float4*)(wcA + (size_t)s * 12);
    w[0] = make_float4(sspv * c0.x, sspv * c0.y, sspv * c0.z, sspv * c0.w);
    w[1] = make_float4(sspv * c1.x, sspv * c1.y, sspv * c1.z, sspv * c1.w);
    w[2] = make_float4(sbv, 0.f, 0.f, 0.f);
}

// ---------------------------------------------------------------------------
// xout sweep v3: thread = (o = t&15, bg = t>>4). OTA=16 o's x IR=16 ii's per
// block; each thread owns one o and 16 b's (b = bg*16+s). Per i-step: wc
// record read ONCE per thread (3 LDS reads, 2-way alias = free), basis tile
// read once per block (waves partition b). VALU-bound by design.
// Epilogue: padded LDS transpose -> fully coalesced xpart writes.
// xpart: [I/16][O][BATCH]
// ---------------------------------------------------------------------------
template <int I, int O>
__device__ __forceinline__ void xout_body(
    const float4* __restrict__ basA4, const float* __restrict__ siluT,
    const float* __restrict__ wcA, float* __restrict__ xpart, int og, int sp)
{
    constexpr int OTA = 16, IR = 16;
    __shared__ float4 wcs[OTA * IR * 3];   // [(i*16+o)*3 + h], 12 KB
    __shared__ float ldsX[16 * 257];       // [o][b] padded, 16.4 KB

    int t = threadIdx.x;
    int o = t & 15, bg = t >> 4;
    int ii0 = sp * IR;

    // stage wc i-major: float4 f -> rec=f/3 (i*16+o2), h=f%3
#pragma unroll
    for (int u = 0; u < 3; ++u) {
        int f = t + u * 256;
        int rec = f / 3, h = f % 3;
        int i = rec >> 4, o2 = rec & 15;
        wcs[f] = ((const float4*)(wcA + ((size_t)(og * OTA + o2) * I + ii0 + i) * 12))[h];
    }
    __syncthreads();

    float acc[16];
#pragma unroll
    for (int s = 0; s < 16; ++s) acc[s] = 0.f;

    for (int i = 0; i < IR; ++i) {
        int ii = ii0 + i;
        const float* wr = (const float*)&wcs[(i * 16 + o) * 3];
        float4 c0 = ((const float4*)wr)[0];
        float4 c1 = ((const float4*)wr)[1];
        float c8 = wr[8];
        const float4* pA0 = basA4 + (size_t)(ii * 2 + 0) * BATCH + bg * 16;
        const float4* pA1 = basA4 + (size_t)(ii * 2 + 1) * BATCH + bg * 16;
        const float*  pSv = siluT + (size_t)ii * BATCH + bg * 16;
#pragma unroll
        for (int s = 0; s < 16; ++s) {
            float4 a0 = pA0[s];
            float4 a1 = pA1[s];
            float sv = pSv[s];
            float y = sv * c8;
            y = fmaf(a0.x, c0.x, y); y = fmaf(a0.y, c0.y, y);
            y = fmaf(a0.z, c0.z, y); y = fmaf(a0.w, c0.w, y);
            y = fmaf(a1.x, c1.x, y); y = fmaf(a1.y, c1.y, y);
            y = fmaf(a1.z, c1.z, y); y = fmaf(a1.w, c1.w, y);
            acc[s] += y;
        }
    }

    // transpose: write [o][b] (2-way alias), read b-lane-fastest (conflict-free)
#pragma unroll
    for (int s = 0; s < 16; ++s)
        ldsX[o * 257 + bg * 16 + s] = acc[s];
    __syncthreads();
    int b = t;
#pragma unroll
    for (int o2 = 0; o2 < 16; ++o2)
        xpart[((size_t)sp * O + og * OTA + o2) * BATCH + b] = ldsX[o2 * 257 + b];
}

// ---------------------------------------------------------------------------
// stats sweep: thread = ii (ii = isp*256+t), 8 o's, BCH=64 b's per block.
// Reads merged wcA (9 FMA/y). spart: [4][3][O*I]
// ---------------------------------------------------------------------------
template <int I, int O>
__device__ __forceinline__ void stats_body(
    const float* __restrict__ basB, const float* __restrict__ siluN,
    const float* __restrict__ wcA, float* __restrict__ spart,
    int og, int ch, int isp)
{
    constexpr int OTB = 8, BCH = 64;
    const size_t OI = (size_t)O * I;
    int ii = isp * 256 + threadIdx.x;

    float wcr[OTB][9];
#pragma unroll
    for (int o = 0; o < OTB; ++o) {
        size_t s = (size_t)(og * OTB + o) * I + ii;
        const float4* p = (const float4*)(wcA + s * 12);
        float4 c0 = p[0], c1 = p[1];
        wcr[o][0] = c0.x; wcr[o][1] = c0.y; wcr[o][2] = c0.z; wcr[o][3] = c0.w;
        wcr[o][4] = c1.x; wcr[o][5] = c1.y; wcr[o][6] = c1.z; wcr[o][7] = c1.w;
        wcr[o][8] = wcA[s * 12 + 8];
    }

    float aab[OTB], asum[OTB], asq[OTB];
#pragma unroll
    for (int o = 0; o < OTB; ++o) { aab[o] = 0.f; asum[o] = 0.f; asq[o] = 0.f; }

    for (int bl = 0; bl < BCH; ++bl) {
        int b = ch * BCH + bl;
        const float4* ba = (const float4*)(basB + ((size_t)b * I + ii) * 8);
        float4 a0 = ba[0], a1 = ba[1];
        float sv = siluN[(size_t)b * I + ii];
#pragma unroll
        for (int o = 0; o < OTB; ++o) {
            float y = wcr[o][8] * sv;
            y = fmaf(a0.x, wcr[o][0], y); y = fmaf(a0.y, wcr[o][1], y);
            y = fmaf(a0.z, wcr[o][2], y); y = fmaf(a0.w, wcr[o][3], y);
            y = fmaf(a1.x, wcr[o][4], y); y = fmaf(a1.y, wcr[o][5], y);
            y = fmaf(a1.z, wcr[o][6], y); y = fmaf(a1.w, wcr[o][7], y);
            aab[o] += fabsf(y);
            asum[o] += y;
            asq[o] = fmaf(y, y, asq[o]);
        }
    }

    size_t cb = (size_t)ch * 3 * OI;
#pragma unroll
    for (int o = 0; o < OTB; ++o) {
        size_t s = (size_t)(og * OTB + o) * I + ii;
        spart[cb + s]          = aab[o];
        spart[cb + OI + s]     = asum[o];
        spart[cb + 2 * OI + s] = asq[o];
    }
}

__device__ __forceinline__ void statsfin_body(
    const float* __restrict__ spart, const float* __restrict__ grid,
    float* __restrict__ sc, float* __restrict__ st, int size, int s)
{
    float ab = 0.f, sm = 0.f, sq = 0.f;
#pragma unroll
    for (int k = 0; k < 4; ++k) {
        size_t base = (size_t)k * 3 * (size_t)size;
        ab += spart[base + s];
        sm += spart[base + (size_t)size + s];
        sq += spart[base + 2 * (size_t)size + s];
    }
    float range = grid[(size_t)s * 6 + 5] - grid[(size_t)s * 6 + 0] + 1e-4f;
    sc[s] = (ab * (1.0f / BATCH)) / range;
    float var = (sq - sm * sm * (1.0f / BATCH)) * (1.0f / (BATCH - 1));
    st[s] = sqrtf(fmaxf(var, 0.0f));
}

// ---------------------------------------------------------------------------
// K1: merge0(512) | basis0-dual(256 tiles, LDS transpose)     -> 768 blocks
// ---------------------------------------------------------------------------
__global__ __launch_bounds__(256) void k1_prep(
    const float* __restrict__ coef0, const float* __restrict__ ssp0,
    const float* __restrict__ sb0, float* __restrict__ wcA0,
    const float* __restrict__ x, const float* __restrict__ grid0,
    float4* __restrict__ basA0, float* __restrict__ siluT0,
    float* __restrict__ basB0, float* __restrict__ siluN0)
{
    __shared__ float lds[9][16][17];
    int bid = blockIdx.x, t = threadIdx.x;
    if (bid < 512)  { merge_body(coef0, ssp0, sb0, wcA0, bid * 256 + t); return; }
    int tile = bid - 512;                  // 16 bt x 16 it
    int bt = tile / 16, it = tile % 16;
    // phase 1: ii lane-fastest -> dense basB/siluN writes
    {
        int ii = it * 16 + (t & 15), b = bt * 16 + (t >> 4);
        float out[9];
        basis_eval(x[(size_t)b * 256 + ii], grid0, ii, out);
        float4* pB = (float4*)(basB0 + ((size_t)b * 256 + ii) * 8);
        pB[0] = make_float4(out[0], out[1], out[2], out[3]);
        pB[1] = make_float4(out[4], out[5], out[6], out[7]);
        siluN0[(size_t)b * 256 + ii] = out[8];
#pragma unroll
        for (int p = 0; p < 9; ++p) lds[p][t & 15][t >> 4] = out[p];
    }
    __syncthreads();
    // phase 2: b lane-fastest -> dense basA/siluT writes
    {
        int ii = it * 16 + (t >> 4), b = bt * 16 + (t & 15);
        float o[9];
#pragma unroll
        for (int p = 0; p < 9; ++p) o[p] = lds[p][t >> 4][t & 15];
        basA0[(size_t)(ii * 2 + 0) * BATCH + b] = make_float4(o[0], o[1], o[2], o[3]);
        basA0[(size_t)(ii * 2 + 1) * BATCH + b] = make_float4(o[4], o[5], o[6], o[7]);
        siluT0[(size_t)ii * BATCH + b] = o[8];
    }
}

// ---------------------------------------------------------------------------
// K2: xout0 (512: og32 x sp16) | stats0 (256: og64 x ch4) | merge1 (512)
//                                                          -> 1280 blocks
// ---------------------------------------------------------------------------
__global__ __launch_bounds__(256) void k2_sweep0(
    const float4* __restrict__ basA0, const float* __restrict__ siluT0,
    const float* __restrict__ wcA0, float* __restrict__ xpart0,
    const float* __restrict__ basB0, const float* __restrict__ siluN0,
    float* __restrict__ spart0,
    const float* __restrict__ coef1, const float* __restrict__ ssp1,
    const float* __restrict__ sb1, float* __restrict__ wcA1)
{
    int bid = blockIdx.x;
    if (bid < 512) {
        xout_body<256, 512>(basA0, siluT0, wcA0, xpart0, bid / 16, bid % 16);
    } else if (bid < 768) {
        int r = bid - 512;   // og in [0,64), ch in [0,4)
        stats_body<256, 512>(basB0, siluN0, wcA0, spart0, r / 4, r % 4, 0);
    } else {
        merge_body(coef1, ssp1, sb1, wcA1, (bid - 768) * 256 + threadIdx.x);
    }
}

// ---------------------------------------------------------------------------
// K3: basis1-dual (512 tiles, fused xmid, LDS transpose) | statsfin0 (512)
// ---------------------------------------------------------------------------
__global__ __launch_bounds__(256) void k3_basis1(
    const float* __restrict__ xpart0, const float* __restrict__ bias0,
    const float* __restrict__ grid1,
    float4* __restrict__ basA1, float* __restrict__ siluT1,
    float* __restrict__ basB1, float* __restrict__ siluN1,
    const float* __restrict__ spart0, const float* __restrict__ grid0,
    float* __restrict__ sc0, float* __restrict__ st0)
{
    __shared__ float lds[9][16][17];
    int bid = blockIdx.x, t = threadIdx.x;
    if (bid < 512) {
        int bt = bid / 32, it = bid % 32;       // b tiles 16, ii tiles 32 (I=512)
        // phase 1: b lane-fastest -> coalesced xpart reads, dense basA writes
        {
            int ii = it * 16 + (t >> 4), b = bt * 16 + (t & 15);
            float xv = bias0[ii];
#pragma unroll
            for (int k = 0; k < 16; ++k)
                xv += xpart0[(size_t)k * 131072 + (size_t)ii * 256 + b];
            float out[9];
            basis_eval(xv, grid1, ii, out);
            basA1[(size_t)(ii * 2 + 0) * BATCH + b] = make_float4(out[0], out[1], out[2], out[3]);
            basA1[(size_t)(ii * 2 + 1) * BATCH + b] = make_float4(out[4], out[5], out[6], out[7]);
            siluT1[(size_t)ii * BATCH + b] = out[8];
#pragma unroll
            for (int p = 0; p < 9; ++p) lds[p][t >> 4][t & 15] = out[p];
        }
        __syncthreads();
        // phase 2: ii lane-fastest -> dense basB/siluN writes
        {
            int ii = it * 16 + (t & 15), b = bt * 16 + (t >> 4);
            float o[9];
#pragma unroll
            for (int p = 0; p < 9; ++p) o[p] = lds[p][t & 15][t >> 4];
            float4* pB = (float4*)(basB1 + ((size_t)b * 512 + ii) * 8);
            pB[0] = make_float4(o[0], o[1], o[2], o[3]);
            pB[1] = make_float4(o[4], o[5], o[6], o[7]);
            siluN1[(size_t)b * 512 + ii] = o[8];
        }
        return;
    }
    statsfin_body(spart0, grid0, sc0, st0, 131072, (bid - 512) * 256 + t);
}

// ---------------------------------------------------------------------------
// K4: xout1 (512: og16 x sp32) | stats1 (256: og32 x ch4 x isp2) -> 768 blocks
// ---------------------------------------------------------------------------
__global__ __launch_bounds__(256) void k4_sweep1(
    const float4* __restrict__ basA1, const float* __restrict__ siluT1,
    const float* __restrict__ wcA1, float* __restrict__ xpart1,
    const float* __restrict__ basB1, const float* __restrict__ siluN1,
    float* __restrict__ spart1)
{
    int bid = blockIdx.x;
    if (bid < 512) {
        xout_body<512, 256>(basA1, siluT1, wcA1, xpart1, bid / 32, bid % 32);
    } else {
        int r = bid - 512;   // og in [0,32), rem: ch in [0,4), isp in {0,1}
        int og = r / 8, rem = r % 8;
        stats_body<512, 256>(basB1, siluN1, wcA1, spart1, og, rem % 4, rem / 4);
    }
}

// ---------------------------------------------------------------------------
// K5: xoutfin1 (256) | statsfin1 (512)                       -> 768 blocks
// ---------------------------------------------------------------------------
__global__ __launch_bounds__(256) void k5_fin(
    const float* __restrict__ xpart1, const float* __restrict__ bias1,
    float* __restrict__ x2,
    const float* __restrict__ spart1, const float* __restrict__ grid1,
    float* __restrict__ sc1, float* __restrict__ st1)
{
    int bid = blockIdx.x, t = threadIdx.x;
    if (bid < 256) {
        int oo = bid, b = t;
        float v = bias1[oo];
#pragma unroll
        for (int k = 0; k < 32; ++k)
            v += xpart1[(size_t)k * 65536 + (size_t)oo * 256 + b];
        x2[(size_t)b * 256 + oo] = v;
    } else {
        statsfin_body(spart1, grid1, sc1, st1, 131072, (bid - 256) * 256 + t);
    }
}

// ---------------------------------------------------------------------------
extern "C" void kernel_launch(void* const* d_in, const int* in_sizes, int n_in,
                              void* d_out, int out_size, void* d_ws, size_t ws_size,
                              hipStream_t stream)
{
    const float* x     = (const float*)d_in[0];
    const float* grid0 = (const float*)d_in[1];
    const float* coef0 = (const float*)d_in[2];
    const float* sb0   = (const float*)d_in[3];
    const float* ssp0  = (const float*)d_in[4];
    const float* bias0 = (const float*)d_in[5];
    const float* grid1 = (const float*)d_in[6];
    const float* coef1 = (const float*)d_in[7];
    const float* sb1   = (const float*)d_in[8];
    const float* ssp1  = (const float*)d_in[9];
    const float* bias1 = (const float*)d_in[10];

    float* out = (float*)d_out;
    float* x2  = out;                 // (256,256)
    float* sc0 = out + 65536;         // (512,256)
    float* st0 = out + 196608;        // (512,256)
    float* sc1 = out + 327680;        // (256,512)
    float* st1 = out + 458752;        // (256,512)

    // Workspace (~56 MB, all disjoint):
    float* w = (float*)d_ws;
    float* basA0  = w; w += 256 * 256 * 8;
    float* siluT0 = w; w += 256 * 256;
    float* basB0  = w; w += 256 * 256 * 8;
    float* siluN0 = w; w += 256 * 256;
    float* basA1  = w; w += 512 * 256 * 8;
    float* siluT1 = w; w += 512 * 256;
    float* basB1  = w; w += 512 * 256 * 8;
    float* siluN1 = w; w += 512 * 256;
    float* wcA0   = w; w += 12 * 512 * 256;
    float* wcA1   = w; w += 12 * 512 * 256;
    float* xpart0 = w; w += 16 * 512 * 256;     // [16][512][256]
    float* xpart1 = w; w += 32 * 256 * 256;     // [32][256][256]
    float* spart0 = w; w += 4 * 3 * 512 * 256;  // [4][3][131072]
    float* spart1 = w; w += 4 * 3 * 256 * 512;  // [4][3][131072]

    k1_prep<<<768, 256, 0, stream>>>(
        coef0, ssp0, sb0, wcA0,
        x, grid0, (float4*)basA0, siluT0, basB0, siluN0);

    k2_sweep0<<<1280, 256, 0, stream>>>(
        (const float4*)basA0, siluT0, wcA0, xpart0, basB0, siluN0, spart0,
        coef1, ssp1, sb1, wcA1);

    k3_basis1<<<1024, 256, 0, stream>>>(
        xpart0, bias0, grid1, (float4*)basA1, siluT1, basB1, siluN1,
        spart0, grid0, sc0, st0);

    k4_sweep1<<<768, 256, 0, stream>>>(
        (const float4*)basA1, siluT1, wcA1, xpart1, basB1, siluN1, spart1);

    k5_fin<<<768, 256, 0, stream>>>(
        xpart1, bias1, x2, spart1, grid1, sc1, st1);
}

// Round 9
// 78.776 us; speedup vs baseline: 1.4795x; 1.4795x over previous
//
#include <hip/hip_runtime.h>
#include <math.h>

constexpr int BATCH = 256;

typedef short short8 __attribute__((ext_vector_type(8)));
typedef float f32x4 __attribute__((ext_vector_type(4)));

// ---------------------------------------------------------------------------
// bf16 helpers (RNE)
// ---------------------------------------------------------------------------
__device__ __forceinline__ unsigned short f2bf(float f) {
    unsigned int u = __float_as_uint(f);
    u += 0x7FFFu + ((u >> 16) & 1u);
    return (unsigned short)(u >> 16);
}
__device__ __forceinline__ float bf2f(unsigned short h) {
    return __uint_as_float(((unsigned int)h) << 16);
}

// ---------------------------------------------------------------------------
// basis_eval: 8 cubic B-spline values + silu. out[0..7]=basis, out[8]=silu.
// ---------------------------------------------------------------------------
__device__ __forceinline__ void basis_eval(
    float x, const float* __restrict__ grid, int ii, float out[9])
{
    float g[6];
#pragma unroll
    for (int k = 0; k < 6; ++k) g[k] = grid[(size_t)ii * 6 + k];
    float h = (g[5] - g[0]) * 0.2f;

    float t[12];
    t[0] = g[0] - 3.f * h; t[1] = g[0] - 2.f * h; t[2] = g[0] - h;
#pragma unroll
    for (int k = 0; k < 6; ++k) t[3 + k] = g[k];
    t[9] = g[5] + h; t[10] = g[5] + 2.f * h; t[11] = g[5] + 3.f * h;

    float Bv[11];
#pragma unroll
    for (int j = 0; j < 11; ++j)
        Bv[j] = (x >= t[j] && x < t[j + 1]) ? 1.0f : 0.0f;

#pragma unroll
    for (int d = 1; d <= 3; ++d) {
#pragma unroll
        for (int j = 0; j + d < 11; ++j) {
            float left  = __fdividef(x - t[j],         t[j + d] - t[j]);
            float right = __fdividef(t[j + d + 1] - x, t[j + d + 1] - t[j + 1]);
            Bv[j] = left * Bv[j] + right * Bv[j + 1];
        }
    }

#pragma unroll
    for (int k = 0; k < 8; ++k) out[k] = Bv[k];
    out[8] = __fdividef(x, 1.0f + __expf(-x));
}

// store 12 floats (last 3 zero) as a 24B bf16 record at rec (8B aligned)
__device__ __forceinline__ void store_rec12(unsigned short* rec, const float v[12])
{
    unsigned int u[6];
#pragma unroll
    for (int j = 0; j < 6; ++j)
        u[j] = (unsigned int)f2bf(v[2 * j]) | ((unsigned int)f2bf(v[2 * j + 1]) << 16);
    uint2* p = (uint2*)rec;
    p[0] = make_uint2(u[0], u[1]);
    p[1] = make_uint2(u[2], u[3]);
    p[2] = make_uint2(u[4], u[5]);
}

// load a 24B record -> 9 floats
__device__ __forceinline__ void load_rec12(const unsigned short* rec, float f[9])
{
    const uint2* p = (const uint2*)rec;
    uint2 q0 = p[0], q1 = p[1], q2 = p[2];
    f[0] = bf2f((unsigned short)q0.x); f[1] = bf2f((unsigned short)(q0.x >> 16));
    f[2] = bf2f((unsigned short)q0.y); f[3] = bf2f((unsigned short)(q0.y >> 16));
    f[4] = bf2f((unsigned short)q1.x); f[5] = bf2f((unsigned short)(q1.x >> 16));
    f[6] = bf2f((unsigned short)q1.y); f[7] = bf2f((unsigned short)(q1.y >> 16));
    f[8] = bf2f((unsigned short)q2.x);
}

// ---------------------------------------------------------------------------
// merge: wc9 record s (= o*I+ii): [ssp*coef0..7, sb, 0,0,0] bf16
// ---------------------------------------------------------------------------
__device__ __forceinline__ void merge_body(
    const float* __restrict__ coef, const float* __restrict__ ssp,
    const float* __restrict__ sb, unsigned short* __restrict__ wc9, int s)
{
    float sspv = ssp[s], sbv = sb[s];
    const float4* c = (const float4*)(coef + (size_t)s * 8);
    float4 c0 = c[0], c1 = c[1];
    float v[12] = { sspv * c0.x, sspv * c0.y, sspv * c0.z, sspv * c0.w,
                    sspv * c1.x, sspv * c1.y, sspv * c1.z, sspv * c1.w,
                    sbv, 0.f, 0.f, 0.f };
    store_rec12(wc9 + (size_t)s * 12, v);
}

// ---------------------------------------------------------------------------
// MFMA GEMM: D[m][n] = sum_k A[m][k]*B[n][k]  (both packs row-major [row][K2]
// bf16, fragment-linear). Block: 4 waves, tile m=16 x n=64; K-split KS.
// part: [KS][M][N] f32 (every element written -> no init needed).
// ---------------------------------------------------------------------------
template <int M, int N, int K2, int KS>
__device__ __forceinline__ void gemm_body(
    const unsigned short* __restrict__ A, const unsigned short* __restrict__ B,
    float* __restrict__ part, int bid)
{
    constexpr int NT = N / 64;
    constexpr int KSTEPS = K2 / KS / 32;
    int ks = bid % KS; int tmp = bid / KS;
    int nt = tmp % NT; int mt = tmp / NT;
    int t = threadIdx.x, l = t & 63, w = t >> 6;
    int m0 = mt * 16, n0 = nt * 64 + w * 16;

    const unsigned short* pa = A + (size_t)(m0 + (l & 15)) * K2 + ks * (K2 / KS) + ((l >> 4) * 8);
    const unsigned short* pb = B + (size_t)(n0 + (l & 15)) * K2 + ks * (K2 / KS) + ((l >> 4) * 8);

    f32x4 acc = {0.f, 0.f, 0.f, 0.f};
#pragma unroll 4
    for (int kk = 0; kk < KSTEPS; ++kk) {
        short8 av = *(const short8*)(pa); pa += 32;
        short8 bv = *(const short8*)(pb); pb += 32;
        acc = __builtin_amdgcn_mfma_f32_16x16x32_bf16(av, bv, acc, 0, 0, 0);
    }

    int n = l & 15, mb = (l >> 4) * 4;
    float* dst = part + ((size_t)ks * M + m0 + mb) * N + n0 + n;
#pragma unroll
    for (int r = 0; r < 4; ++r) dst[(size_t)r * N] = acc[r];
}

// ---------------------------------------------------------------------------
// stats sweep: thread = ii (ii = isp*256+t), 8 o's in regs, BCH=32 b's/block.
// Reads bf16 records (24B each). spart: [8][3][O*I]
// ---------------------------------------------------------------------------
template <int I, int O>
__device__ __forceinline__ void stats_body(
    const unsigned short* __restrict__ bas9, const unsigned short* __restrict__ wc9,
    float* __restrict__ spart, int og, int ch, int isp)
{
    constexpr int OTB = 8, BCH = 32;
    const size_t OI = (size_t)O * I;
    int ii = isp * 256 + threadIdx.x;

    float wcr[OTB][9];
#pragma unroll
    for (int o = 0; o < OTB; ++o)
        load_rec12(wc9 + ((size_t)(og * OTB + o) * I + ii) * 12, wcr[o]);

    float aab[OTB], asum[OTB], asq[OTB];
#pragma unroll
    for (int o = 0; o < OTB; ++o) { aab[o] = 0.f; asum[o] = 0.f; asq[o] = 0.f; }

    for (int bl = 0; bl < BCH; ++bl) {
        int b = ch * BCH + bl;
        float f[9];
        load_rec12(bas9 + ((size_t)b * I + ii) * 12, f);
#pragma unroll
        for (int o = 0; o < OTB; ++o) {
            float y = wcr[o][8] * f[8];
#pragma unroll
            for (int p = 0; p < 8; ++p) y = fmaf(f[p], wcr[o][p], y);
            aab[o] += fabsf(y);
            asum[o] += y;
            asq[o] = fmaf(y, y, asq[o]);
        }
    }

    size_t cb = (size_t)ch * 3 * OI;
#pragma unroll
    for (int o = 0; o < OTB; ++o) {
        size_t s = (size_t)(og * OTB + o) * I + ii;
        spart[cb + s]          = aab[o];
        spart[cb + OI + s]     = asum[o];
        spart[cb + 2 * OI + s] = asq[o];
    }
}

__device__ __forceinline__ void statsfin_body(
    const float* __restrict__ spart, const float* __restrict__ grid,
    float* __restrict__ sc, float* __restrict__ st, int size, int s)
{
    float ab = 0.f, sm = 0.f, sq = 0.f;
#pragma unroll
    for (int k = 0; k < 8; ++k) {
        size_t base = (size_t)k * 3 * (size_t)size;
        ab += spart[base + s];
        sm += spart[base + (size_t)size + s];
        sq += spart[base + 2 * (size_t)size + s];
    }
    float range = grid[(size_t)s * 6 + 5] - grid[(size_t)s * 6 + 0] + 1e-4f;
    sc[s] = (ab * (1.0f / BATCH)) / range;
    float var = (sq - sm * sm * (1.0f / BATCH)) * (1.0f / (BATCH - 1));
    st[s] = sqrtf(fmaxf(var, 0.0f));
}

// ---------------------------------------------------------------------------
// K1: merge0(512) | basis0(256, ii-lane-fast)                -> 768 blocks
// ---------------------------------------------------------------------------
__global__ __launch_bounds__(256) void k1_prep(
    const float* __restrict__ coef0, const float* __restrict__ ssp0,
    const float* __restrict__ sb0, unsigned short* __restrict__ wc9_0,
    const float* __restrict__ x, const float* __restrict__ grid0,
    unsigned short* __restrict__ bas9_0)
{
    int bid = blockIdx.x, t = threadIdx.x;
    if (bid < 512) { merge_body(coef0, ssp0, sb0, wc9_0, bid * 256 + t); return; }
    int tile = bid - 512;                  // 16 bt x 16 it
    int bt = tile >> 4, it = tile & 15;
    int ii = it * 16 + (t & 15), b = bt * 16 + (t >> 4);
    float out[12];
    basis_eval(x[(size_t)b * 256 + ii], grid0, ii, out);
    out[9] = 0.f; out[10] = 0.f; out[11] = 0.f;
    store_rec12(bas9_0 + ((size_t)b * 256 + ii) * 12, out);
}

// ---------------------------------------------------------------------------
// K2: gemm0(512) | stats0(512) | merge1(512)                 -> 1536 blocks
// gemm0: A=wc9_0 (m=o, M=512), B=bas9_0 (n=b, N=256), K2=3072, KS=4
// ---------------------------------------------------------------------------
__global__ __launch_bounds__(256) void k2_sweep0(
    const unsigned short* __restrict__ wc9_0, const unsigned short* __restrict__ bas9_0,
    float* __restrict__ gxp0, float* __restrict__ spart0,
    const float* __restrict__ coef1, const float* __restrict__ ssp1,
    const float* __restrict__ sb1, unsigned short* __restrict__ wc9_1)
{
    int bid = blockIdx.x;
    if (bid < 512) {
        gemm_body<512, 256, 3072, 4>(wc9_0, bas9_0, gxp0, bid);
    } else if (bid < 1024) {
        int r = bid - 512;   // og in [0,64), ch in [0,8)
        stats_body<256, 512>(bas9_0, wc9_0, spart0, r >> 3, r & 7, 0);
    } else {
        merge_body(coef1, ssp1, sb1, wc9_1, (bid - 1024) * 256 + threadIdx.x);
    }
}

// ---------------------------------------------------------------------------
// K3: basis1(512 tiles, fused xmid via LDS transpose) | statsfin0(512)
// ---------------------------------------------------------------------------
__global__ __launch_bounds__(256) void k3_basis1(
    const float* __restrict__ gxp0, const float* __restrict__ bias0,
    const float* __restrict__ grid1, unsigned short* __restrict__ bas9_1,
    const float* __restrict__ spart0, const float* __restrict__ grid0,
    float* __restrict__ sc0, float* __restrict__ st0)
{
    __shared__ float lds[16][17];
    int bid = blockIdx.x, t = threadIdx.x;
    if (bid < 512) {
        int bt = bid >> 5, it = bid & 31;   // 16 b-tiles x 32 ii-tiles (I=512)
        // phase A: b lane-fast, coalesced gxp0 reads
        {
            int ii = it * 16 + (t >> 4), b = bt * 16 + (t & 15);
            float xv = bias0[ii];
#pragma unroll
            for (int ks = 0; ks < 4; ++ks)
                xv += gxp0[((size_t)ks * 512 + ii) * 256 + b];
            lds[t >> 4][t & 15] = xv;
        }
        __syncthreads();
        // phase B: ii lane-fast, eval + dense record writes
        {
            int ii = it * 16 + (t & 15), b = bt * 16 + (t >> 4);
            float out[12];
            basis_eval(lds[t & 15][t >> 4], grid1, ii, out);
            out[9] = 0.f; out[10] = 0.f; out[11] = 0.f;
            store_rec12(bas9_1 + ((size_t)b * 512 + ii) * 12, out);
        }
        return;
    }
    statsfin_body(spart0, grid0, sc0, st0, 131072, (bid - 512) * 256 + t);
}

// ---------------------------------------------------------------------------
// K4: gemm1(512) | stats1(512)                               -> 1024 blocks
// gemm1: A=bas9_1 (m=b, M=256), B=wc9_1 (n=o, N=256), K2=6144, KS=8
// ---------------------------------------------------------------------------
__global__ __launch_bounds__(256) void k4_sweep1(
    const unsigned short* __restrict__ bas9_1, const unsigned short* __restrict__ wc9_1,
    float* __restrict__ gxp1, float* __restrict__ spart1)
{
    int bid = blockIdx.x;
    if (bid < 512) {
        gemm_body<256, 256, 6144, 8>(bas9_1, wc9_1, gxp1, bid);
    } else {
        int r = bid - 512;   // og in [0,32), ch in [0,8), isp in {0,1}
        int og = r >> 4, rem = r & 15;
        stats_body<512, 256>(bas9_1, wc9_1, spart1, og, rem & 7, rem >> 3);
    }
}

// ---------------------------------------------------------------------------
// K5: xoutfin1(256) | statsfin1(512)                         -> 768 blocks
// ---------------------------------------------------------------------------
__global__ __launch_bounds__(256) void k5_fin(
    const float* __restrict__ gxp1, const float* __restrict__ bias1,
    float* __restrict__ x2,
    const float* __restrict__ spart1, const float* __restrict__ grid1,
    float* __restrict__ sc1, float* __restrict__ st1)
{
    int bid = blockIdx.x, t = threadIdx.x;
    if (bid < 256) {
        int idx = bid * 256 + t;
        int b = idx >> 8, o = idx & 255;
        float v = bias1[o];
#pragma unroll
        for (int ks = 0; ks < 8; ++ks)
            v += gxp1[((size_t)ks * 256 + b) * 256 + o];
        x2[(size_t)b * 256 + o] = v;
    } else {
        statsfin_body(spart1, grid1, sc1, st1, 131072, (bid - 256) * 256 + t);
    }
}

// ---------------------------------------------------------------------------
extern "C" void kernel_launch(void* const* d_in, const int* in_sizes, int n_in,
                              void* d_out, int out_size, void* d_ws, size_t ws_size,
                              hipStream_t stream)
{
    const float* x     = (const float*)d_in[0];
    const float* grid0 = (const float*)d_in[1];
    const float* coef0 = (const float*)d_in[2];
    const float* sb0   = (const float*)d_in[3];
    const float* ssp0  = (const float*)d_in[4];
    const float* bias0 = (const float*)d_in[5];
    const float* grid1 = (const float*)d_in[6];
    const float* coef1 = (const float*)d_in[7];
    const float* sb1   = (const float*)d_in[8];
    const float* ssp1  = (const float*)d_in[9];
    const float* bias1 = (const float*)d_in[10];

    float* out = (float*)d_out;
    float* x2  = out;                 // (256,256)
    float* sc0 = out + 65536;         // (512,256)
    float* st0 = out + 196608;        // (512,256)
    float* sc1 = out + 327680;        // (256,512)
    float* st1 = out + 458752;        // (256,512)

    // Workspace (~37 MB, all disjoint)
    char* w = (char*)d_ws;
    unsigned short* wc9_0  = (unsigned short*)w; w += (size_t)512 * 3072 * 2;
    unsigned short* wc9_1  = (unsigned short*)w; w += (size_t)256 * 6144 * 2;
    unsigned short* bas9_0 = (unsigned short*)w; w += (size_t)256 * 3072 * 2;
    unsigned short* bas9_1 = (unsigned short*)w; w += (size_t)256 * 6144 * 2;
    float* gxp0   = (float*)w; w += (size_t)4 * 512 * 256 * 4;
    float* gxp1   = (float*)w; w += (size_t)8 * 256 * 256 * 4;
    float* spart0 = (float*)w; w += (size_t)8 * 3 * 131072 * 4;
    float* spart1 = (float*)w; w += (size_t)8 * 3 * 131072 * 4;

    k1_prep<<<768, 256, 0, stream>>>(
        coef0, ssp0, sb0, wc9_0, x, grid0, bas9_0);

    k2_sweep0<<<1536, 256, 0, stream>>>(
        wc9_0, bas9_0, gxp0, spart0, coef1, ssp1, sb1, wc9_1);

    k3_basis1<<<1024, 256, 0, stream>>>(
        gxp0, bias0, grid1, bas9_1, spart0, grid0, sc0, st0);

    k4_sweep1<<<1024, 256, 0, stream>>>(
        bas9_1, wc9_1, gxp1, spart1);

    k5_fin<<<768, 256, 0, stream>>>(
        gxp1, bias1, x2, spart1, grid1, sc1, st1);
}

// Round 10
// 75.072 us; speedup vs baseline: 1.5525x; 1.0493x over previous
//
#include <hip/hip_runtime.h>
#include <math.h>

constexpr int BATCH = 256;

typedef short short8 __attribute__((ext_vector_type(8)));
typedef float f32x4 __attribute__((ext_vector_type(4)));

// ---------------------------------------------------------------------------
// bf16 helpers (RNE)
// ---------------------------------------------------------------------------
__device__ __forceinline__ unsigned short f2bf(float f) {
    unsigned int u = __float_as_uint(f);
    u += 0x7FFFu + ((u >> 16) & 1u);
    return (unsigned short)(u >> 16);
}
__device__ __forceinline__ float bf2f(unsigned short h) {
    return __uint_as_float(((unsigned int)h) << 16);
}

// ---------------------------------------------------------------------------
// basis_eval: 8 cubic B-spline values + silu. out[0..7]=basis, out[8]=silu.
// ---------------------------------------------------------------------------
__device__ __forceinline__ void basis_eval(
    float x, const float* __restrict__ grid, int ii, float out[9])
{
    float g[6];
#pragma unroll
    for (int k = 0; k < 6; ++k) g[k] = grid[(size_t)ii * 6 + k];
    float h = (g[5] - g[0]) * 0.2f;

    float t[12];
    t[0] = g[0] - 3.f * h; t[1] = g[0] - 2.f * h; t[2] = g[0] - h;
#pragma unroll
    for (int k = 0; k < 6; ++k) t[3 + k] = g[k];
    t[9] = g[5] + h; t[10] = g[5] + 2.f * h; t[11] = g[5] + 3.f * h;

    float Bv[11];
#pragma unroll
    for (int j = 0; j < 11; ++j)
        Bv[j] = (x >= t[j] && x < t[j + 1]) ? 1.0f : 0.0f;

#pragma unroll
    for (int d = 1; d <= 3; ++d) {
#pragma unroll
        for (int j = 0; j + d < 11; ++j) {
            float left  = __fdividef(x - t[j],         t[j + d] - t[j]);
            float right = __fdividef(t[j + d + 1] - x, t[j + d + 1] - t[j + 1]);
            Bv[j] = left * Bv[j] + right * Bv[j + 1];
        }
    }

#pragma unroll
    for (int k = 0; k < 8; ++k) out[k] = Bv[k];
    out[8] = __fdividef(x, 1.0f + __expf(-x));
}

// store 12 floats (last 3 zero) as a 24B bf16 record at rec (8B aligned)
__device__ __forceinline__ void store_rec12(unsigned short* rec, const float v[12])
{
    unsigned int u[6];
#pragma unroll
    for (int j = 0; j < 6; ++j)
        u[j] = (unsigned int)f2bf(v[2 * j]) | ((unsigned int)f2bf(v[2 * j + 1]) << 16);
    uint2* p = (uint2*)rec;
    p[0] = make_uint2(u[0], u[1]);
    p[1] = make_uint2(u[2], u[3]);
    p[2] = make_uint2(u[4], u[5]);
}

// load a 24B record -> 9 floats
__device__ __forceinline__ void load_rec12(const unsigned short* rec, float f[9])
{
    const uint2* p = (const uint2*)rec;
    uint2 q0 = p[0], q1 = p[1], q2 = p[2];
    f[0] = bf2f((unsigned short)q0.x); f[1] = bf2f((unsigned short)(q0.x >> 16));
    f[2] = bf2f((unsigned short)q0.y); f[3] = bf2f((unsigned short)(q0.y >> 16));
    f[4] = bf2f((unsigned short)q1.x); f[5] = bf2f((unsigned short)(q1.x >> 16));
    f[6] = bf2f((unsigned short)q1.y); f[7] = bf2f((unsigned short)(q1.y >> 16));
    f[8] = bf2f((unsigned short)q2.x);
}

// ---------------------------------------------------------------------------
// merge: wc9 record s (= o*I+ii): [ssp*coef0..7, sb, 0,0,0] bf16
// ---------------------------------------------------------------------------
__device__ __forceinline__ void merge_body(
    const float* __restrict__ coef, const float* __restrict__ ssp,
    const float* __restrict__ sb, unsigned short* __restrict__ wc9, int s)
{
    float sspv = ssp[s], sbv = sb[s];
    const float4* c = (const float4*)(coef + (size_t)s * 8);
    float4 c0 = c[0], c1 = c[1];
    float v[12] = { sspv * c0.x, sspv * c0.y, sspv * c0.z, sspv * c0.w,
                    sspv * c1.x, sspv * c1.y, sspv * c1.z, sspv * c1.w,
                    sbv, 0.f, 0.f, 0.f };
    store_rec12(wc9 + (size_t)s * 12, v);
}

// ---------------------------------------------------------------------------
// MFMA GEMM: D[m][n] = sum_k A[m][k]*B[n][k]  (both packs row-major [row][K2]
// bf16, fragment-linear). Block: 4 waves, tile m=16 x n=64; K-split KS.
// part: [KS][M][N] f32 (every element written -> no init needed).
// ---------------------------------------------------------------------------
template <int M, int N, int K2, int KS>
__device__ __forceinline__ void gemm_body(
    const unsigned short* __restrict__ A, const unsigned short* __restrict__ B,
    float* __restrict__ part, int bid)
{
    constexpr int NT = N / 64;
    constexpr int KSTEPS = K2 / KS / 32;
    int ks = bid % KS; int tmp = bid / KS;
    int nt = tmp % NT; int mt = tmp / NT;
    int t = threadIdx.x, l = t & 63, w = t >> 6;
    int m0 = mt * 16, n0 = nt * 64 + w * 16;

    const unsigned short* pa = A + (size_t)(m0 + (l & 15)) * K2 + ks * (K2 / KS) + ((l >> 4) * 8);
    const unsigned short* pb = B + (size_t)(n0 + (l & 15)) * K2 + ks * (K2 / KS) + ((l >> 4) * 8);

    f32x4 acc = {0.f, 0.f, 0.f, 0.f};
#pragma unroll 4
    for (int kk = 0; kk < KSTEPS; ++kk) {
        short8 av = *(const short8*)(pa); pa += 32;
        short8 bv = *(const short8*)(pb); pb += 32;
        acc = __builtin_amdgcn_mfma_f32_16x16x32_bf16(av, bv, acc, 0, 0, 0);
    }

    int n = l & 15, mb = (l >> 4) * 4;
    float* dst = part + ((size_t)ks * M + m0 + mb) * N + n0 + n;
#pragma unroll
    for (int r = 0; r < 4; ++r) dst[(size_t)r * N] = acc[r];
}

// ---------------------------------------------------------------------------
// stats sweep: thread = ii (ii = isp*256+t), 8 o's in regs, BCH=32 b's/block.
// Reads bf16 records (24B each). spart: [8][3][O*I]
// ---------------------------------------------------------------------------
template <int I, int O>
__device__ __forceinline__ void stats_body(
    const unsigned short* __restrict__ bas9, const unsigned short* __restrict__ wc9,
    float* __restrict__ spart, int og, int ch, int isp)
{
    constexpr int OTB = 8, BCH = 32;
    const size_t OI = (size_t)O * I;
    int ii = isp * 256 + threadIdx.x;

    float wcr[OTB][9];
#pragma unroll
    for (int o = 0; o < OTB; ++o)
        load_rec12(wc9 + ((size_t)(og * OTB + o) * I + ii) * 12, wcr[o]);

    float aab[OTB], asum[OTB], asq[OTB];
#pragma unroll
    for (int o = 0; o < OTB; ++o) { aab[o] = 0.f; asum[o] = 0.f; asq[o] = 0.f; }

    for (int bl = 0; bl < BCH; ++bl) {
        int b = ch * BCH + bl;
        float f[9];
        load_rec12(bas9 + ((size_t)b * I + ii) * 12, f);
#pragma unroll
        for (int o = 0; o < OTB; ++o) {
            float y = wcr[o][8] * f[8];
#pragma unroll
            for (int p = 0; p < 8; ++p) y = fmaf(f[p], wcr[o][p], y);
            aab[o] += fabsf(y);
            asum[o] += y;
            asq[o] = fmaf(y, y, asq[o]);
        }
    }

    size_t cb = (size_t)ch * 3 * OI;
#pragma unroll
    for (int o = 0; o < OTB; ++o) {
        size_t s = (size_t)(og * OTB + o) * I + ii;
        spart[cb + s]          = aab[o];
        spart[cb + OI + s]     = asum[o];
        spart[cb + 2 * OI + s] = asq[o];
    }
}

__device__ __forceinline__ void statsfin_body(
    const float* __restrict__ spart, const float* __restrict__ grid,
    float* __restrict__ sc, float* __restrict__ st, int size, int s)
{
    float ab = 0.f, sm = 0.f, sq = 0.f;
#pragma unroll
    for (int k = 0; k < 8; ++k) {
        size_t base = (size_t)k * 3 * (size_t)size;
        ab += spart[base + s];
        sm += spart[base + (size_t)size + s];
        sq += spart[base + 2 * (size_t)size + s];
    }
    float range = grid[(size_t)s * 6 + 5] - grid[(size_t)s * 6 + 0] + 1e-4f;
    sc[s] = (ab * (1.0f / BATCH)) / range;
    float var = (sq - sm * sm * (1.0f / BATCH)) * (1.0f / (BATCH - 1));
    st[s] = sqrtf(fmaxf(var, 0.0f));
}

// ---------------------------------------------------------------------------
// K1: merge0(512) | basis0(256, ii-lane-fast)                -> 768 blocks
// ---------------------------------------------------------------------------
__global__ __launch_bounds__(256) void k1_prep(
    const float* __restrict__ coef0, const float* __restrict__ ssp0,
    const float* __restrict__ sb0, unsigned short* __restrict__ wc9_0,
    const float* __restrict__ x, const float* __restrict__ grid0,
    unsigned short* __restrict__ bas9_0)
{
    int bid = blockIdx.x, t = threadIdx.x;
    if (bid < 512) { merge_body(coef0, ssp0, sb0, wc9_0, bid * 256 + t); return; }
    int tile = bid - 512;                  // 16 bt x 16 it
    int bt = tile >> 4, it = tile & 15;
    int ii = it * 16 + (t & 15), b = bt * 16 + (t >> 4);
    float out[12];
    basis_eval(x[(size_t)b * 256 + ii], grid0, ii, out);
    out[9] = 0.f; out[10] = 0.f; out[11] = 0.f;
    store_rec12(bas9_0 + ((size_t)b * 256 + ii) * 12, out);
}

// ---------------------------------------------------------------------------
// K2: gemm0(512) | merge1(512)                               -> 1024 blocks
// gemm0: A=wc9_0 (m=o, M=512), B=bas9_0 (n=b, N=256), K2=3072, KS=4
// ---------------------------------------------------------------------------
__global__ __launch_bounds__(256) void k2_gemm0(
    const unsigned short* __restrict__ wc9_0, const unsigned short* __restrict__ bas9_0,
    float* __restrict__ gxp0,
    const float* __restrict__ coef1, const float* __restrict__ ssp1,
    const float* __restrict__ sb1, unsigned short* __restrict__ wc9_1)
{
    int bid = blockIdx.x;
    if (bid < 512) {
        gemm_body<512, 256, 3072, 4>(wc9_0, bas9_0, gxp0, bid);
    } else {
        merge_body(coef1, ssp1, sb1, wc9_1, (bid - 512) * 256 + threadIdx.x);
    }
}

// ---------------------------------------------------------------------------
// K3: basis1 only (512 tiles, fused xmid via LDS transpose)
// ---------------------------------------------------------------------------
__global__ __launch_bounds__(256) void k3_basis1(
    const float* __restrict__ gxp0, const float* __restrict__ bias0,
    const float* __restrict__ grid1, unsigned short* __restrict__ bas9_1)
{
    __shared__ float lds[16][17];
    int bid = blockIdx.x, t = threadIdx.x;
    int bt = bid >> 5, it = bid & 31;   // 16 b-tiles x 32 ii-tiles (I=512)
    // phase A: b lane-fast, coalesced gxp0 reads
    {
        int ii = it * 16 + (t >> 4), b = bt * 16 + (t & 15);
        float xv = bias0[ii];
#pragma unroll
        for (int ks = 0; ks < 4; ++ks)
            xv += gxp0[((size_t)ks * 512 + ii) * 256 + b];
        lds[t >> 4][t & 15] = xv;
    }
    __syncthreads();
    // phase B: ii lane-fast, eval + dense record writes
    {
        int ii = it * 16 + (t & 15), b = bt * 16 + (t >> 4);
        float out[12];
        basis_eval(lds[t & 15][t >> 4], grid1, ii, out);
        out[9] = 0.f; out[10] = 0.f; out[11] = 0.f;
        store_rec12(bas9_1 + ((size_t)b * 512 + ii) * 12, out);
    }
}

// ---------------------------------------------------------------------------
// K4: gemm1(512) | stats0(512) | stats1(512)                 -> 1536 blocks
// gemm1: A=bas9_1 (m=b, M=256), B=wc9_1 (n=o, N=256), K2=6144, KS=8
// ---------------------------------------------------------------------------
__global__ __launch_bounds__(256) void k4_sweep(
    const unsigned short* __restrict__ bas9_1, const unsigned short* __restrict__ wc9_1,
    float* __restrict__ gxp1, float* __restrict__ spart1,
    const unsigned short* __restrict__ bas9_0, const unsigned short* __restrict__ wc9_0,
    float* __restrict__ spart0)
{
    int bid = blockIdx.x;
    if (bid < 512) {
        gemm_body<256, 256, 6144, 8>(bas9_1, wc9_1, gxp1, bid);
    } else if (bid < 1024) {
        int r = bid - 512;   // og in [0,64), ch in [0,8)
        stats_body<256, 512>(bas9_0, wc9_0, spart0, r >> 3, r & 7, 0);
    } else {
        int r = bid - 1024;  // og in [0,32), ch in [0,8), isp in {0,1}
        int og = r >> 4, rem = r & 15;
        stats_body<512, 256>(bas9_1, wc9_1, spart1, og, rem & 7, rem >> 3);
    }
}

// ---------------------------------------------------------------------------
// K5: xoutfin1(256) | statsfin0(512) | statsfin1(512)        -> 1280 blocks
// ---------------------------------------------------------------------------
__global__ __launch_bounds__(256) void k5_fin(
    const float* __restrict__ gxp1, const float* __restrict__ bias1,
    float* __restrict__ x2,
    const float* __restrict__ spart0, const float* __restrict__ grid0,
    float* __restrict__ sc0, float* __restrict__ st0,
    const float* __restrict__ spart1, const float* __restrict__ grid1,
    float* __restrict__ sc1, float* __restrict__ st1)
{
    int bid = blockIdx.x, t = threadIdx.x;
    if (bid < 256) {
        int idx = bid * 256 + t;
        int b = idx >> 8, o = idx & 255;
        float v = bias1[o];
#pragma unroll
        for (int ks = 0; ks < 8; ++ks)
            v += gxp1[((size_t)ks * 256 + b) * 256 + o];
        x2[(size_t)b * 256 + o] = v;
    } else if (bid < 768) {
        statsfin_body(spart0, grid0, sc0, st0, 131072, (bid - 256) * 256 + t);
    } else {
        statsfin_body(spart1, grid1, sc1, st1, 131072, (bid - 768) * 256 + t);
    }
}

// ---------------------------------------------------------------------------
extern "C" void kernel_launch(void* const* d_in, const int* in_sizes, int n_in,
                              void* d_out, int out_size, void* d_ws, size_t ws_size,
                              hipStream_t stream)
{
    const float* x     = (const float*)d_in[0];
    const float* grid0 = (const float*)d_in[1];
    const float* coef0 = (const float*)d_in[2];
    const float* sb0   = (const float*)d_in[3];
    const float* ssp0  = (const float*)d_in[4];
    const float* bias0 = (const float*)d_in[5];
    const float* grid1 = (const float*)d_in[6];
    const float* coef1 = (const float*)d_in[7];
    const float* sb1   = (const float*)d_in[8];
    const float* ssp1  = (const float*)d_in[9];
    const float* bias1 = (const float*)d_in[10];

    float* out = (float*)d_out;
    float* x2  = out;                 // (256,256)
    float* sc0 = out + 65536;         // (512,256)
    float* st0 = out + 196608;        // (512,256)
    float* sc1 = out + 327680;        // (256,512)
    float* st1 = out + 458752;        // (256,512)

    // Workspace (~37 MB, all disjoint)
    char* w = (char*)d_ws;
    unsigned short* wc9_0  = (unsigned short*)w; w += (size_t)512 * 3072 * 2;
    unsigned short* wc9_1  = (unsigned short*)w; w += (size_t)256 * 6144 * 2;
    unsigned short* bas9_0 = (unsigned short*)w; w += (size_t)256 * 3072 * 2;
    unsigned short* bas9_1 = (unsigned short*)w; w += (size_t)256 * 6144 * 2;
    float* gxp0   = (float*)w; w += (size_t)4 * 512 * 256 * 4;
    float* gxp1   = (float*)w; w += (size_t)8 * 256 * 256 * 4;
    float* spart0 = (float*)w; w += (size_t)8 * 3 * 131072 * 4;
    float* spart1 = (float*)w; w += (size_t)8 * 3 * 131072 * 4;

    k1_prep<<<768, 256, 0, stream>>>(
        coef0, ssp0, sb0, wc9_0, x, grid0, bas9_0);

    k2_gemm0<<<1024, 256, 0, stream>>>(
        wc9_0, bas9_0, gxp0, coef1, ssp1, sb1, wc9_1);

    k3_basis1<<<512, 256, 0, stream>>>(
        gxp0, bias0, grid1, bas9_1);

    k4_sweep<<<1536, 256, 0, stream>>>(
        bas9_1, wc9_1, gxp1, spart1, bas9_0, wc9_0, spart0);

    k5_fin<<<1280, 256, 0, stream>>>(
        gxp1, bias1, x2, spart0, grid0, sc0, st0, spart1, grid1, sc1, st1);
}